// Round 1
// baseline (465.531 us; speedup 1.0000x reference)
//
#include <hip/hip_runtime.h>
#include <stdint.h>

// Problem constants
#define NN   16
#define HH   112
#define WW   112
#define CIN  256
#define COUT 256
#define HP   114          // padded height
#define WP   114          // padded width
#define M_TOTAL (NN * HH * WW)                    // 200704
#define XP_BYTES ((size_t)NN * HP * WP * CIN)     // 53,231,616
#define WPK_BYTES ((size_t)9 * COUT * CIN)        // 589,824

typedef int v4i __attribute__((ext_vector_type(4)));

__device__ __forceinline__ void load_lds16(const void* g, void* l) {
  __builtin_amdgcn_global_load_lds(
      (const __attribute__((address_space(1))) void*)g,
      (__attribute__((address_space(3))) void*)l, 16, 0, 0);
}

// register-only byte pack: 4 ints (int8-valued) -> one dword
__device__ __forceinline__ int pack4(int a, int b, int c, int d) {
  return (a & 255) | ((b & 255) << 8) | ((c & 255) << 16) | (d << 24);
}

// ---------------- pack x: int32 NHWC -> int8 padded [N][114][114][256] ----------------
// One thread per 16 consecutive ints: 64 B of loads (4x dwordx4), one 16 B packed
// store (full-width coalescing on BOTH sides). 12544 blocks.
__global__ void pack_x_kernel(const int* __restrict__ x, char* __restrict__ xp) {
  int t = blockIdx.x * 256 + threadIdx.x;   // exactly M_TOTAL*16 threads
  int g = t & 15;                           // 16B-group within pixel (16 ci each)
  int p = t >> 4;                           // pixel index
  int w = p % WW;
  int t2 = p / WW;
  int h = t2 % HH;
  int n = t2 / HH;
  const int4* src = (const int4*)(x + (size_t)t * 16);
  int4 a = src[0], b = src[1], c = src[2], d = src[3];
  int4 ov;
  ov.x = pack4(a.x, a.y, a.z, a.w);
  ov.y = pack4(b.x, b.y, b.z, b.w);
  ov.z = pack4(c.x, c.y, c.z, c.w);
  ov.w = pack4(d.x, d.y, d.z, d.w);
  size_t dst = (((size_t)n * HP + (h + 1)) * WP + (w + 1)) * CIN + (size_t)g * 16;
  *(int4*)(xp + dst) = ov;
}

// ---------------- fused: pack weight (blocks 0..575) + zero border (blocks 576..1027) ----
__global__ void pack_w_border_kernel(const int* __restrict__ wgt, char* __restrict__ xp,
                                     char* __restrict__ wp) {
  int bid = blockIdx.x;
  if (bid < 576) {
    // pack weight: OHWI int32 -> int8 [tap][cout][cin]
    int t = bid * 256 + threadIdx.x;        // exactly 2304*64 threads
    int c4 = t & 63;                        // dword within (tap,cout) row
    int r = t >> 6;                         // 0..2303 = cout*9 + tap
    int tap = r % 9;
    int cout = r / 9;
    int4 v = *(const int4*)(wgt + (size_t)t * 4);
    int ov = pack4(v.x, v.y, v.z, v.w);
    size_t dst = ((size_t)tap * COUT + cout) * CIN + (size_t)c4 * 4;
    *(int*)(wp + dst) = ov;
  } else {
    // zero the 1-pixel border of xp
    int t = (bid - 576) * 256 + threadIdx.x;  // exactly 452*256 threads
    int g = t & 15;
    int pix = t >> 4;                          // 0..7231
    int n = pix / 452;
    int b = pix % 452;
    int h, w;
    if (b < 114) { h = 0; w = b; }
    else if (b < 228) { h = 113; w = b - 114; }
    else { int r = b - 228; h = 1 + (r >> 1); w = (r & 1) ? 113 : 0; }
    size_t dst = (((size_t)n * HP + h) * WP + w) * CIN + (size_t)g * 16;
    *(int4*)(xp + dst) = make_int4(0, 0, 0, 0);
  }
}

// ---------------- implicit-GEMM conv: C[M=200704][256] = A[M][2304] * B[2304][256] ----------------
// A[m][(tap,ci)] = xp[pixel(m) shifted by tap][ci]; B stored as wp[tap][cout][ci].
// Tile: 128x256 (full COUT per block), BK=64, 4 waves in 2x2; each wave 64m x 128n
// = 4x8 MFMA 16x16x64 tiles.
//
// Pipeline (T3+T4+T5 from the 8-phase template): TRIPLE-buffered LDS, staging for
// step ks+2 issued during step ks (split 3+3 across two phases), raw s_barrier +
// manual counted waits. vmcnt never drains to 0 in the main loop: at end of step ks
// the outstanding queue is {6 loads for ks+1, 6 for ks+2} -> vmcnt(6) retires only
// the ks+1 set while ks+2 stays in flight across the barrier. Each phase computes a
// 16-MFMA cluster wrapped in s_setprio(1/0).
__global__ __launch_bounds__(256, 2) void conv_mfma_kernel(const char* __restrict__ xp,
                                                           const char* __restrict__ wp,
                                                           int* __restrict__ out) {
  __shared__ __align__(16) char As[3 * 128 * 64];   // 24 KB (triple buffer)
  __shared__ __align__(16) char Bs[3 * 256 * 64];   // 48 KB (triple buffer)
  const int tid = threadIdx.x;
  const int lane = tid & 63;
  const int wave = tid >> 6;
  const int mtile = blockIdx.x;

  // ---- staging: 24 chunks of 1 KB (A: 0..7, B: 8..23); each wave stages 6 ----
  // LDS layout per tile: row-major [rows][4 cols of 16B], column XOR-swizzled:
  // position (row, c) holds global 16B-column (c ^ ((row>>1)&3)).
  const char* gptr[6];
  char* lptr[6];     // base within buffer 0
  int  isA[6];
#pragma unroll
  for (int j = 0; j < 6; j++) {
    int c = wave * 6 + j;                 // chunk 0..23
    if (c < 8) {
      int row = c * 16 + (lane >> 2);     // A tile row
      int colg = (lane & 3) ^ ((row >> 1) & 3);
      int m = mtile * 128 + row;
      int w = m % WW;
      int t2 = m / WW;
      int h = t2 % HH;
      int n = t2 / HH;
      gptr[j] = xp + (((size_t)n * HP + h) * WP + w) * CIN + (size_t)colg * 16;
      lptr[j] = As + c * 1024;
      isA[j] = 1;
    } else {
      int cb = c - 8;
      int row = cb * 16 + (lane >> 2);    // B row = cout 0..255
      int colg = (lane & 3) ^ ((row >> 1) & 3);
      gptr[j] = wp + (size_t)row * CIN + (size_t)colg * 16;
      lptr[j] = Bs + cb * 1024;
      isA[j] = 0;
    }
  }

  // ---- compute fragment LDS offsets (within buffer 0) ----
  const int wm = wave & 1;   // m half (64 rows)
  const int wn = wave >> 1;  // n half (128 cols)
  int aoff[4], boff[8];
#pragma unroll
  for (int i = 0; i < 4; i++) {
    int ra = wm * 64 + i * 16 + (lane & 15);
    aoff[i] = ra * 64 + (((lane >> 4) ^ ((ra >> 1) & 3)) * 16);
  }
#pragma unroll
  for (int j = 0; j < 8; j++) {
    int rb = wn * 128 + j * 16 + (lane & 15);
    boff[j] = rb * 64 + (((lane >> 4) ^ ((rb >> 1) & 3)) * 16);
  }

  v4i acc[4][8];
#pragma unroll
  for (int i = 0; i < 4; i++)
#pragma unroll
    for (int j = 0; j < 8; j++) acc[i][j] = (v4i){0, 0, 0, 0};

  // stage half (3 chunks) of step ks into buffer b (b in {0,1,2})
  auto stage_half = [&](int ks, int b, int half) {
    int tap = ks >> 2;
    int kb = ks & 3;
    int ky = tap / 3;
    int kx = tap - ky * 3;
    int offA = (ky * WP + kx) * CIN + kb * 64;
    int offB = tap * (COUT * CIN) + kb * 64;
#pragma unroll
    for (int j = half * 3; j < half * 3 + 3; j++)
      load_lds16(gptr[j] + (isA[j] ? offA : offB),
                 lptr[j] + (isA[j] ? b * 8192 : b * 16384));
  };

  // prologue: steps 0 and 1 staged; wait only for step 0 (step 1 stays in flight)
  stage_half(0, 0, 0); stage_half(0, 0, 1);
  stage_half(1, 1, 0); stage_half(1, 1, 1);
  asm volatile("s_waitcnt vmcnt(6)" ::: "memory");
  __builtin_amdgcn_s_barrier();

  int bc = 0;   // buffer being read (= ks % 3)
  int bs = 2;   // buffer being staged (= (ks+2) % 3)
#pragma unroll 1
  for (int ks = 0; ks < 36; ks++) {
    const char* Ab = As + bc * 8192;
    const char* Bb = Bs + bc * 16384;
    v4i af[4], bf[8];

    // ---- phase A: read af[0..3], bf[0..3]; issue 3 prefetch loads; 16 MFMA ----
#pragma unroll
    for (int i = 0; i < 4; i++) af[i] = *(const v4i*)(Ab + aoff[i]);
#pragma unroll
    for (int j = 0; j < 4; j++) bf[j] = *(const v4i*)(Bb + boff[j]);
    if (ks < 34) stage_half(ks + 2, bs, 0);
    __builtin_amdgcn_s_barrier();
    asm volatile("s_waitcnt lgkmcnt(0)" ::: "memory");
    __builtin_amdgcn_s_setprio(1);
#pragma unroll
    for (int i = 0; i < 4; i++)
#pragma unroll
      for (int j = 0; j < 4; j++)
        acc[i][j] = __builtin_amdgcn_mfma_i32_16x16x64_i8(af[i], bf[j], acc[i][j], 0, 0, 0);
    __builtin_amdgcn_s_setprio(0);
    __builtin_amdgcn_s_barrier();

    // ---- phase B: read bf[4..7]; issue remaining 3 prefetch loads; 16 MFMA ----
#pragma unroll
    for (int j = 4; j < 8; j++) bf[j] = *(const v4i*)(Bb + boff[j]);
    if (ks < 34) stage_half(ks + 2, bs, 1);
    __builtin_amdgcn_s_barrier();
    asm volatile("s_waitcnt lgkmcnt(0)" ::: "memory");
    __builtin_amdgcn_s_setprio(1);
#pragma unroll
    for (int i = 0; i < 4; i++)
#pragma unroll
      for (int j = 4; j < 8; j++)
        acc[i][j] = __builtin_amdgcn_mfma_i32_16x16x64_i8(af[i], bf[j], acc[i][j], 0, 0, 0);
    __builtin_amdgcn_s_setprio(0);

    // end-of-step: retire ONLY the loads for step ks+1; ks+2's stay in flight
    if (ks < 34)       asm volatile("s_waitcnt vmcnt(6)" ::: "memory");
    else if (ks == 34) asm volatile("s_waitcnt vmcnt(0)" ::: "memory");
    __builtin_amdgcn_s_barrier();

    bc = (bc == 2) ? 0 : bc + 1;
    bs = (bs == 2) ? 0 : bs + 1;
  }

  // ---- epilogue: C/D layout col=lane&15, row=(lane>>4)*4+reg ----
#pragma unroll
  for (int i = 0; i < 4; i++) {
    const int mg = mtile * 128 + wm * 64 + i * 16 + ((lane >> 4) * 4);
#pragma unroll
    for (int r = 0; r < 4; r++) {
      int* orow = out + (size_t)(mg + r) * COUT + wn * 128 + (lane & 15);
#pragma unroll
      for (int j = 0; j < 8; j++) orow[j * 16] = acc[i][j][r];
    }
  }
}

// ---------------- fallback (only if ws too small): direct int32 conv ----------------
__global__ void conv_naive_kernel(const int* __restrict__ x, const int* __restrict__ wgt,
                                  int* __restrict__ out, int total) {
  int idx = blockIdx.x * 256 + threadIdx.x;
  if (idx >= total) return;
  int co = idx & 255;
  int p = idx >> 8;
  int w = p % WW;
  int t2 = p / WW;
  int h = t2 % HH;
  int n = t2 / HH;
  int acc = 0;
  for (int ky = 0; ky < 3; ky++) {
    int ih = h + ky - 1;
    if (ih < 0 || ih >= HH) continue;
    for (int kx = 0; kx < 3; kx++) {
      int iw = w + kx - 1;
      if (iw < 0 || iw >= WW) continue;
      const int* xs = x + (((size_t)n * HH + ih) * WW + iw) * CIN;
      const int* ws = wgt + ((size_t)co * 9 + ky * 3 + kx) * CIN;
      for (int ci = 0; ci < CIN; ci++) acc += xs[ci] * ws[ci];
    }
  }
  out[idx] = acc;
}

extern "C" void kernel_launch(void* const* d_in, const int* in_sizes, int n_in,
                              void* d_out, int out_size, void* d_ws, size_t ws_size,
                              hipStream_t stream) {
  const int* x = (const int*)d_in[0];
  const int* wgt = (const int*)d_in[1];
  int* out = (int*)d_out;
  const size_t need = XP_BYTES + WPK_BYTES;
  if (ws_size >= need) {
    char* xp = (char*)d_ws;
    char* wp = xp + XP_BYTES;
    pack_x_kernel<<<(M_TOTAL * 16) / 256, 256, 0, stream>>>(x, xp);       // 12544 blocks
    pack_w_border_kernel<<<576 + 452, 256, 0, stream>>>(wgt, xp, wp);     // 1028 blocks
    conv_mfma_kernel<<<M_TOTAL / 128, 256, 0, stream>>>(xp, wp, out);     // 1568 blocks
  } else {
    conv_naive_kernel<<<(out_size + 255) / 256, 256, 0, stream>>>(x, wgt, out, out_size);
  }
}